// Round 1
// baseline (470.250 us; speedup 1.0000x reference)
//
#include <hip/hip_runtime.h>
#include <math.h>

// Problem constants: B=2, D_e=128, D_o=256, T=16, H=W=64, H_ref=W_ref=32, s=2, k=32
// n_blocks = T*H_ref*W_ref = 16384 per batch; HW_ref = 1024 query blocks per batch.

// ---------------- workspace layout (bytes) ----------------
// [0, 134217728)      : qk_T [2][1024][16384] f32   (later reused as m_out_b [2][16384][4][256])
// [134217728, +64MB)  : m_in_b [2][16384][4][128] f32
// [201326592, +4MB)   : q_b [2][1024][4][128] f32
// [205520896, +256KB) : idx_sorted [2][1024][32] int32

// ---------------- kernel 1: transpose qk_ref [B,16384,1024] -> [B,1024,16384] ----------------
// 128x128 tile, 512 threads, float4 both global sides (512B segments/wave), loads staged
// in registers (8 outstanding 1KB wave-loads) before LDS writes. XOR swizzle keeps LDS
// store conflicts ~4-way; LDS time is far under the HBM budget per tile.
__global__ __launch_bounds__(512) void transpose_qk(const float* __restrict__ in,
                                                    float* __restrict__ out) {
    __shared__ float tile[128][132];   // [q][r^g], pitch 132 keeps float4 reads 16B-aligned
    int r0 = blockIdx.x * 128;
    int q0 = blockIdx.y * 128;
    int b  = blockIdx.z;
    const float* src = in  + (size_t)b * 16384 * 1024;
    float*       dst = out + (size_t)b * 1024 * 16384;
    int tid = threadIdx.x;

    // phase 1: load 128 rows x 128 q, float4 per thread, explicitly staged in regs
    {
        int qi = (tid & 31) * 4;       // 32 threads x float4 = 512B per row segment
        int rr = tid >> 5;             // 0..15
        const float* s0 = src + (size_t)(r0 + rr) * 1024 + q0 + qi;
        float4 v[8];
#pragma unroll
        for (int p = 0; p < 8; ++p)
            v[p] = *(const float4*)(s0 + (size_t)p * 16 * 1024);
#pragma unroll
        for (int p = 0; p < 8; ++p) {
            int r = p * 16 + rr;
#pragma unroll
            for (int j = 0; j < 4; ++j) {
                int q = qi + j;
                int g = ((q >> 2) & 7) << 2;
                tile[q][r ^ g] = ((const float*)&v[p])[j];
            }
        }
    }
    __syncthreads();

    // phase 2: write 128 q-rows x 128 r, float4 (512B segments/wave)
    {
        int rr4 = (tid & 31) * 4;
        int qq  = tid >> 5;            // 0..15
#pragma unroll
        for (int p = 0; p < 8; ++p) {
            int q = p * 16 + qq;
            int g = ((q >> 2) & 7) << 2;
            float4 w = *(const float4*)&tile[q][rr4 ^ g];
            *(float4*)(dst + (size_t)(q0 + q) * 16384 + r0 + rr4) = w;
        }
    }
}

// ---------------- kernel 2: top-32 via threshold filter + rank select ----------------
// 512 thr/wg, one wg per (b,q). Thread owns 32 reg-resident values (float4 loads).
// Monotonic u32 transform; 2-pass histogram of the 512 THREAD-MAXIMA gives a provably
// conservative threshold t (<= 32nd-largest global). Filter to ~45 candidates, exact
// top-32 by rank counting on packed (uval, 16383-idx) u64 keys (jax tie order).
__device__ inline unsigned mono_u32(float f) {
    unsigned b = __float_as_uint(f);
    return (b & 0x80000000u) ? ~b : (b | 0x80000000u);
}

__global__ __launch_bounds__(512) void topk_kernel(const float* __restrict__ qk_T,
                                                   float* __restrict__ out_idx,
                                                   float* __restrict__ out_val,
                                                   int* __restrict__ idx_sorted) {
    int bid = blockIdx.x;              // b*1024 + q
    int tid = threadIdx.x;
    const float4* row4 = (const float4*)(qk_T + (size_t)bid * 16384);

    float v[32];
#pragma unroll
    for (int g = 0; g < 8; ++g) {
        float4 t4 = row4[g * 512 + tid];      // float idx g*2048 + tid*4
        v[g * 4 + 0] = t4.x; v[g * 4 + 1] = t4.y;
        v[g * 4 + 2] = t4.z; v[g * 4 + 3] = t4.w;
    }
    // gi(e) = (e>>2)*2048 + tid*4 + (e&3)  — monotone in e for fixed thread

    float cv = v[0]; int ci = 0;       // thread max (lowest e on tie -> lowest gi)
#pragma unroll
    for (int e = 1; e < 32; ++e) { if (v[e] > cv) { cv = v[e]; ci = e; } }

    __shared__ int hist1[256];
    __shared__ int hist2[256];
    __shared__ int s_b1, s_above1, s_cnt;
    __shared__ unsigned s_tu;
    __shared__ unsigned long long cand[512];
    __shared__ unsigned long long selk[32];
    __shared__ float wvf[2][8];
    __shared__ int   wif[2][8];

    if (tid < 256) { hist1[tid] = 0; hist2[tid] = 0; }
    if (tid == 0) s_cnt = 0;
    __syncthreads();

    unsigned um = mono_u32(cv);
    atomicAdd(&hist1[um >> 24], 1);
    __syncthreads();

    // pass 1: find byte b1 containing rank-32 of maxima (from top), count strictly above
    if (tid < 64) {
        int base = 252 - 4 * tid;      // lane 0 covers top bins 252..255
        int h0 = hist1[base], h1 = hist1[base + 1], h2 = hist1[base + 2], h3 = hist1[base + 3];
        int gs = h0 + h1 + h2 + h3;
        int pre = gs;
#pragma unroll
        for (int off = 1; off < 64; off <<= 1) {
            int o = __shfl_up(pre, off, 64);
            if (tid >= off) pre += o;
        }
        int excl = pre - gs;           // maxima in higher groups
        if (excl < 32 && pre >= 32) {  // crossing group (exactly one lane)
            int c = excl, b, ab;
            c += h3; if (c >= 32) { b = base + 3; ab = c - h3; }
            else { c += h2; if (c >= 32) { b = base + 2; ab = c - h2; }
            else { c += h1; if (c >= 32) { b = base + 1; ab = c - h1; }
            else { c += h0;   b = base;     ab = c - h0; } } }
            s_b1 = b; s_above1 = ab;
        }
    }
    __syncthreads();
    int b1 = s_b1;
    if ((int)(um >> 24) == b1) atomicAdd(&hist2[(um >> 16) & 0xFF], 1);
    __syncthreads();

    // pass 2: refine to 16-bit prefix floor
    if (tid < 64) {
        int A = s_above1;
        int base = 252 - 4 * tid;
        int h0 = hist2[base], h1 = hist2[base + 1], h2 = hist2[base + 2], h3 = hist2[base + 3];
        int gs = h0 + h1 + h2 + h3;
        int pre = gs;
#pragma unroll
        for (int off = 1; off < 64; off <<= 1) {
            int o = __shfl_up(pre, off, 64);
            if (tid >= off) pre += o;
        }
        int excl = pre - gs;
        if (A + excl < 32 && A + pre >= 32) {
            int c = A + excl, b;
            c += h3; if (c >= 32) b = base + 3;
            else { c += h2; if (c >= 32) b = base + 2;
            else { c += h1; if (c >= 32) b = base + 1;
            else { b = base; } } }
            s_tu = (((unsigned)b1 << 8) | (unsigned)b) << 16;
        }
    }
    __syncthreads();
    unsigned tu = s_tu;

    // filter: keep values with u >= tu (superset of global top-32)
#pragma unroll
    for (int e = 0; e < 32; ++e) {
        unsigned ue = mono_u32(v[e]);
        if (ue >= tu) {
            int pos = atomicAdd(&s_cnt, 1);
            if (pos < 512) {
                int gi = (e >> 2) * 2048 + tid * 4 + (e & 3);
                cand[pos] = ((unsigned long long)ue << 32) |
                            (unsigned long long)(16383 - gi);
            }
        }
    }
    __syncthreads();
    int C = s_cnt;

    if (C <= 512) {
        if (tid < C) {
            unsigned long long mine = cand[tid];
            int rank = 0;
            for (int j = 0; j < C; ++j) rank += (cand[j] > mine) ? 1 : 0;
            if (rank < 32) selk[rank] = mine;
        }
        __syncthreads();
    } else {
        // fallback (pathological duplicates only): iterative extraction, exact
        unsigned used = 0u;
        int w = tid >> 6, lane = tid & 63;
#pragma unroll 1
        for (int s = 0; s < 32; ++s) {
            float rv = cv; int ri = (ci >> 2) * 2048 + tid * 4 + (ci & 3);
#pragma unroll
            for (int off = 32; off >= 1; off >>= 1) {
                float ov = __shfl_xor(rv, off, 64);
                int   oi = __shfl_xor(ri, off, 64);
                if (ov > rv || (ov == rv && oi < ri)) { rv = ov; ri = oi; }
            }
            int buf = s & 1;
            if (lane == 0) { wvf[buf][w] = rv; wif[buf][w] = ri; }
            __syncthreads();
            float bv = wvf[buf][0]; int bi = wif[buf][0];
#pragma unroll
            for (int j = 1; j < 8; ++j) {
                float jv = wvf[buf][j]; int ji = wif[buf][j];
                if (jv > bv || (jv == bv && ji < bi)) { bv = jv; bi = ji; }
            }
            if (tid == 0)
                selk[s] = ((unsigned long long)mono_u32(bv) << 32) |
                          (unsigned long long)(16383 - bi);
            if (((bi >> 2) & 511) == tid) {
                int be = ((bi >> 11) << 2) | (bi & 3);
                used |= 1u << be;
                cv = -__builtin_inff(); ci = 0;
#pragma unroll
                for (int e = 0; e < 32; ++e)
                    if (!((used >> e) & 1u) && v[e] > cv) { cv = v[e]; ci = e; }
            }
        }
        __syncthreads();
    }

    if (tid < 8) {
        unsigned long long k = selk[tid];
        unsigned uv = (unsigned)(k >> 32);
        unsigned bits = (uv & 0x80000000u) ? (uv ^ 0x80000000u) : ~uv;
        out_val[(size_t)bid * 8 + tid] = __uint_as_float(bits);
        int gi = 16383 - (int)(k & 0xFFFFFFFFull);
        out_idx[(size_t)bid * 8 + tid] = (float)gi;
    }
    if (tid < 32) {                    // 32 distinct indices -> ascending sort by rank
        int mine = 16383 - (int)(selk[tid] & 0xFFFFFFFFull);
        int rank = 0;
#pragma unroll
        for (int j = 0; j < 32; ++j) {
            int oj = 16383 - (int)(selk[j] & 0xFFFFFFFFull);
            rank += (oj < mine) ? 1 : 0;
        }
        idx_sorted[(size_t)bid * 32 + rank] = mine;
    }
}

// ---------------- kernel 3: LDS-tiled blockify [B,D,T,64,64] -> [B, T*1024, 4, D] ----------------
template <int D, int T>
__global__ __launch_bounds__(256) void blockify_tiled(const float* __restrict__ in,
                                                      float* __restrict__ out) {
    constexpr int NCH = D / 64;
    int wg = blockIdx.x;
    int ch = wg % NCH;
    int hb = (wg / NCH) % 32;
    int t  = (wg / (NCH * 32)) % T;
    int b  = wg / (NCH * 32 * T);
    int c0 = ch * 64;
    int tid = threadIdx.x;

    __shared__ float tile[64][129];

    {
        int x = tid & 63;
        int rw = tid >> 6;
#pragma unroll 8
        for (int i = 0; i < 32; ++i) {
            int r = i * 4 + rw;
            int c = r >> 1, si = r & 1;
            tile[c][si * 64 + x] =
                in[((((size_t)b * D + c0 + c) * T + t) * 64 + (2 * hb + si)) * 64 + x];
        }
    }
    __syncthreads();

    {
        int p = tid >> 6;
        int cc = tid & 63;
        int si = p >> 1, sj = p & 1;
        size_t nbase = (((size_t)b * T + t) * 1024 + (size_t)hb * 32);
#pragma unroll 8
        for (int wb = 0; wb < 32; ++wb) {
            out[(nbase + wb) * 4 * D + (size_t)p * D + c0 + cc] =
                tile[cc][si * 64 + 2 * wb + sj];
        }
    }
}

// ---------------- kernel 4: gathered block attention ----------------
__global__ __launch_bounds__(256) void attn_kernel(const float* __restrict__ m_in_b,
                                                   const float* __restrict__ m_out_b,
                                                   const float* __restrict__ q_b,
                                                   const int* __restrict__ idx_sorted,
                                                   float* __restrict__ out) {
    int bid = blockIdx.x;
    int b = bid >> 10, qblk = bid & 1023;
    int hb = qblk >> 5, wb = qblk & 31;
    int tid = threadIdx.x;
    int w = tid >> 6, lane = tid & 63;

    __shared__ float K[64][129];
    __shared__ float Q[4][128];
    __shared__ float P[4][128];
    __shared__ int   blks[32];

    if (tid < 32) blks[tid] = idx_sorted[(size_t)bid * 32 + tid];
    {
        const float* qsrc = q_b + (size_t)bid * 512;
        ((float*)Q)[tid]       = qsrc[tid];
        ((float*)Q)[tid + 256] = qsrc[tid + 256];
    }
    __syncthreads();

    const float scale = 0.08838834764831845f;
    float s01[2];
#pragma unroll 1
    for (int half = 0; half < 2; ++half) {
        if (half) __syncthreads();
#pragma unroll 4
        for (int ki = 0; ki < 16; ++ki) {
            int blk = blks[half * 16 + ki];
            const float* src = m_in_b + ((size_t)b * 16384 + blk) * 512;
            int p0 = tid >> 7, c0 = tid & 127;
            K[ki * 4 + p0][c0]     = src[tid];
            K[ki * 4 + p0 + 2][c0] = src[tid + 256];
        }
        __syncthreads();
        float acc = 0.f;
#pragma unroll 4
        for (int c = 0; c < 128; ++c) acc += K[lane][c] * Q[w][c];
        s01[half] = acc * scale;
    }

    float m = fmaxf(s01[0], s01[1]);
#pragma unroll
    for (int off = 32; off >= 1; off >>= 1) m = fmaxf(m, __shfl_xor(m, off, 64));
    float e0 = expf(s01[0] - m), e1 = expf(s01[1] - m);
    float sum = e0 + e1;
#pragma unroll
    for (int off = 32; off >= 1; off >>= 1) sum += __shfl_xor(sum, off, 64);
    float inv = 1.0f / sum;
    P[w][lane]      = e0 * inv;
    P[w][lane + 64] = e1 * inv;
    __syncthreads();

    float a0 = 0.f, a1 = 0.f, a2 = 0.f, a3 = 0.f;
    int d = tid;
#pragma unroll 1
    for (int ki = 0; ki < 32; ++ki) {
        const float* vsrc = m_out_b + ((size_t)b * 16384 + blks[ki]) * 1024;
#pragma unroll
        for (int p = 0; p < 4; ++p) {
            float vv = vsrc[p * 256 + d];
            int n = ki * 4 + p;
            a0 += P[0][n] * vv; a1 += P[1][n] * vv;
            a2 += P[2][n] * vv; a3 += P[3][n] * vv;
        }
    }
    size_t base = (((size_t)b * 256 + d) * 64 + hb * 2) * 64 + wb * 2;
    out[base]      = a0;
    out[base + 1]  = a1;
    out[base + 64] = a2;
    out[base + 65] = a3;
}

extern "C" void kernel_launch(void* const* d_in, const int* in_sizes, int n_in,
                              void* d_out, int out_size, void* d_ws, size_t ws_size,
                              hipStream_t stream) {
    const float* m_in  = (const float*)d_in[0];
    const float* m_out = (const float*)d_in[1];
    const float* q_in  = (const float*)d_in[2];
    const float* qk    = (const float*)d_in[3];

    char* ws = (char*)d_ws;
    float* qk_T    = (float*)(ws);
    float* m_out_b = (float*)(ws);                 // reuses qk_T region (stream-ordered)
    float* m_in_b  = (float*)(ws + 134217728);
    float* q_b     = (float*)(ws + 201326592);
    int*   idxs    = (int*)  (ws + 205520896);

    float* out     = (float*)d_out;
    float* out_mem = out;
    float* out_idx = out + 2097152;
    float* out_val = out + 2113536;

    transpose_qk<<<dim3(128, 8, 2), 512, 0, stream>>>(qk, qk_T);
    topk_kernel<<<2048, 512, 0, stream>>>(qk_T, out_idx, out_val, idxs);
    blockify_tiled<128, 16><<<2 * 16 * 32 * 2, 256, 0, stream>>>(m_in, m_in_b);
    blockify_tiled<128, 1><<<2 * 1 * 32 * 2, 256, 0, stream>>>(q_in, q_b);
    blockify_tiled<256, 16><<<2 * 16 * 32 * 4, 256, 0, stream>>>(m_out, m_out_b);
    attn_kernel<<<2048, 256, 0, stream>>>(m_in_b, m_out_b, q_b, idxs, out_mem);
}